// Round 2
// baseline (1050.979 us; speedup 1.0000x reference)
//
#include <hip/hip_runtime.h>
#include <stdint.h>
#include <stddef.h>

#define T_DIM 8192
#define I_DIM 4096
#define O_DIM 11008
#define NW (11008LL * 4096LL)

#define BM 128
#define BN 128
#define BK 64
#define NKT (I_DIM / BK)  // 64

typedef __attribute__((ext_vector_type(4))) int i32x4;

__device__ __forceinline__ void gload_lds16(const void* g, void* l) {
  __builtin_amdgcn_global_load_lds(
      (const __attribute__((address_space(1))) void*)g,
      (__attribute__((address_space(3))) void*)l, 16, 0, 0);
}

__global__ void k_zero(double* p) { *p = 0.0; }

// ---------------- activation quant: per-row amax -> int8 ----------------
__global__ __launch_bounds__(256) void k_actquant(const float* __restrict__ x,
                                                  char* __restrict__ q,
                                                  float* __restrict__ inv_s) {
  __shared__ float smax[4];
  const int row = blockIdx.x;
  const int tid = threadIdx.x;
  const float4* xr = (const float4*)(x + (size_t)row * I_DIM);
  float4 v[4];
  float m = 0.f;
#pragma unroll
  for (int j = 0; j < 4; ++j) {
    v[j] = xr[j * 256 + tid];
    m = fmaxf(m, fmaxf(fmaxf(fabsf(v[j].x), fabsf(v[j].y)),
                       fmaxf(fabsf(v[j].z), fabsf(v[j].w))));
  }
#pragma unroll
  for (int o = 32; o > 0; o >>= 1) m = fmaxf(m, __shfl_xor(m, o));
  if ((tid & 63) == 0) smax[tid >> 6] = m;
  __syncthreads();
  m = fmaxf(fmaxf(smax[0], smax[1]), fmaxf(smax[2], smax[3]));
  m = fmaxf(m, 1e-5f);                     // clip(amax, 1e-5, None)
  const float sact = 127.0f / m;           // quant scale
  if (tid == 0) inv_s[row] = (m + 2e-6f) / 127.0f;  // 1/s with S_EPS
  int* qr = (int*)(q + (size_t)row * I_DIM);
#pragma unroll
  for (int j = 0; j < 4; ++j) {
    float vals[4] = {v[j].x, v[j].y, v[j].z, v[j].w};
    int p = 0;
#pragma unroll
    for (int e = 0; e < 4; ++e) {
      float f = rintf(vals[e] * sact);     // jnp.round = half-to-even
      f = fminf(fmaxf(f, -128.f), 127.f);
      p |= ((int)f & 0xff) << (8 * e);
    }
    qr[j * 256 + tid] = p;
  }
}

// ---------------- mean(|w|) reduce (double accumulate) ----------------
__global__ __launch_bounds__(256) void k_absmean(const float* __restrict__ w,
                                                 double* __restrict__ sum) {
  __shared__ double sacc[4];
  const size_t n4 = (size_t)NW / 4;
  size_t idx = (size_t)blockIdx.x * 256 + threadIdx.x;
  const size_t stride = (size_t)gridDim.x * 256;
  double a = 0.0;
  const float4* w4 = (const float4*)w;
  for (size_t i = idx; i < n4; i += stride) {
    float4 v = w4[i];
    a += (double)fabsf(v.x) + (double)fabsf(v.y) +
         (double)fabsf(v.z) + (double)fabsf(v.w);
  }
#pragma unroll
  for (int o = 32; o > 0; o >>= 1) a += __shfl_xor(a, o);
  const int tid = threadIdx.x;
  if ((tid & 63) == 0) sacc[tid >> 6] = a;
  __syncthreads();
  if (tid == 0) atomicAdd(sum, sacc[0] + sacc[1] + sacc[2] + sacc[3]);
}

__global__ void k_finalize(const double* __restrict__ sum,
                           float* __restrict__ swp) {
  float m = (float)(*sum * (1.0 / (double)NW));
  *swp = 1.0f / fmaxf(m, 1e-5f);
}

// ---------------- ternary weight quant ----------------
__global__ __launch_bounds__(256) void k_wquant(const float* __restrict__ w,
                                                const float* __restrict__ swp,
                                                char* __restrict__ tw) {
  const float sw = *swp;
  const int row = blockIdx.x;
  const int tid = threadIdx.x;
  const float4* wr = (const float4*)(w + (size_t)row * I_DIM);
  int* out = (int*)(tw + (size_t)row * I_DIM);
#pragma unroll
  for (int j = 0; j < 4; ++j) {
    float4 v = wr[j * 256 + tid];
    float vals[4] = {v.x, v.y, v.z, v.w};
    int p = 0;
#pragma unroll
    for (int e = 0; e < 4; ++e) {
      float f = rintf(vals[e] * sw);
      f = fminf(fmaxf(f, -1.f), 1.f);
      p |= ((int)f & 0xff) << (8 * e);
    }
    out[j * 256 + tid] = p;
  }
}

// ---------------- i8 GEMM: C[t,o] = (sum_k q*tw) * inv_s[t] * s_w ----------------
// 128x128 tile, BK=64, 4 waves (2x2), each wave 64x64 = 4x4 frags of 16x16x64.
__global__ __launch_bounds__(256) void k_gemm(const char* __restrict__ Aq,
                                              const char* __restrict__ Bt,
                                              const float* __restrict__ inv_s,
                                              const float* __restrict__ swp,
                                              float* __restrict__ C) {
  __shared__ __align__(16) char lds[2][2][BM * BK];  // [buf][A/B][8KB]
  const int tid = threadIdx.x;
  const int lane = tid & 63;
  const int wid = tid >> 6;
  const int wr = wid >> 1, wc = wid & 1;
  const int brow = blockIdx.y * BM;
  const int bcol = blockIdx.x * BN;

  const int r = lane & 15;            // fragment row/col within 16
  const int kb = (lane >> 4) * 16;    // K byte block within 64

  i32x4 acc[4][4];
#pragma unroll
  for (int a = 0; a < 4; ++a)
#pragma unroll
    for (int b = 0; b < 4; ++b) acc[a][b] = (i32x4){0, 0, 0, 0};

  // staging: instr j covers LDS rows [j*64, j*64+64); thread writes lds off j*4096 + tid*16
  const int srow = tid >> 2;          // 0..63 within the 64-row chunk
  const int scol = (tid & 3) * 16;    // byte offset in K
  const char* gA = Aq + (size_t)(brow + srow) * I_DIM + scol;
  const char* gB = Bt + (size_t)(bcol + srow) * I_DIM + scol;

  auto stage = [&](int buf, int kt) {
    const size_t koff = (size_t)kt * BK;
#pragma unroll
    for (int j = 0; j < 2; ++j) {
      gload_lds16(gA + koff + (size_t)j * 64 * I_DIM,
                  &lds[buf][0][j * 4096 + wid * 1024]);
      gload_lds16(gB + koff + (size_t)j * 64 * I_DIM,
                  &lds[buf][1][j * 4096 + wid * 1024]);
    }
  };

  auto compute = [&](int buf) {
    const char* la = &lds[buf][0][0];
    const char* lb = &lds[buf][1][0];
    i32x4 af[4], bf[4];
#pragma unroll
    for (int mf = 0; mf < 4; ++mf)
      af[mf] = *(const i32x4*)(la + (wr * 64 + mf * 16 + r) * 64 + kb);
#pragma unroll
    for (int nf = 0; nf < 4; ++nf)
      bf[nf] = *(const i32x4*)(lb + (wc * 64 + nf * 16 + r) * 64 + kb);
#pragma unroll
    for (int mf = 0; mf < 4; ++mf)
#pragma unroll
      for (int nf = 0; nf < 4; ++nf)
        acc[mf][nf] = __builtin_amdgcn_mfma_i32_16x16x64_i8(
            af[mf], bf[nf], acc[mf][nf], 0, 0, 0);
  };

  stage(0, 0);
  __syncthreads();
  int cur = 0;
  for (int kt = 0; kt < NKT - 1; ++kt) {
    stage(cur ^ 1, kt + 1);
    compute(cur);
    __syncthreads();
    cur ^= 1;
  }
  compute(cur);

  const float sw = *swp;
#pragma unroll
  for (int mf = 0; mf < 4; ++mf) {
    const int trow0 = brow + wr * 64 + mf * 16 + (lane >> 4) * 4;
#pragma unroll
    for (int nf = 0; nf < 4; ++nf) {
      const int col = bcol + wc * 64 + nf * 16 + r;
#pragma unroll
      for (int e = 0; e < 4; ++e) {
        const int t = trow0 + e;
        C[(size_t)t * O_DIM + col] = (float)acc[mf][nf][e] * (inv_s[t] * sw);
      }
    }
  }
}

extern "C" void kernel_launch(void* const* d_in, const int* in_sizes, int n_in,
                              void* d_out, int out_size, void* d_ws, size_t ws_size,
                              hipStream_t stream) {
  const float* x = (const float*)d_in[0];
  const float* w = (const float*)d_in[1];
  float* out = (float*)d_out;
  char* ws = (char*)d_ws;

  double* sum = (double*)ws;                         // 8 B
  float* swp = (float*)(ws + 8);                     // 4 B
  float* inv_s = (float*)(ws + 256);                 // 32 KB
  char* q = ws + 65536;                              // 33.5 MB int8 [T][I]
  char* tw = ws + 65536 + (size_t)T_DIM * I_DIM;     // 45 MB int8 [O][I]

  k_zero<<<1, 1, 0, stream>>>(sum);
  k_actquant<<<T_DIM, 256, 0, stream>>>(x, q, inv_s);
  k_absmean<<<2048, 256, 0, stream>>>(w, sum);
  k_finalize<<<1, 1, 0, stream>>>(sum, swp);
  k_wquant<<<O_DIM, 256, 0, stream>>>(w, swp, tw);

  dim3 grid(O_DIM / BN, T_DIM / BM);  // 86 x 64
  k_gemm<<<grid, 256, 0, stream>>>(q, tw, inv_s, swp, out);
}